// Round 10
// baseline (463.953 us; speedup 1.0000x reference)
//
#include <hip/hip_runtime.h>
#include <math.h>

#define DIN  512
#define DHID 512
#define DOUT 256

typedef __attribute__((ext_vector_type(8))) short short8;
typedef __attribute__((ext_vector_type(4))) float f32x4;
typedef __attribute__((ext_vector_type(2))) float floatx2;

__device__ __forceinline__ unsigned short f2bf(float f) {
    unsigned int u = __float_as_uint(f);
    u += 0x7fffu + ((u >> 16) & 1u);
    return (unsigned short)(u >> 16);
}
__device__ __forceinline__ float bflo(unsigned int w) { return __uint_as_float(w << 16); }
__device__ __forceinline__ float bfhi(unsigned int w) { return __uint_as_float(w & 0xffff0000u); }

// ---------------------------------------------------------------------------
// fp32 -> bf16, 8 elems per index i
__device__ __forceinline__ void cvt8(const float* __restrict__ in,
                                     unsigned short* __restrict__ out, int i) {
    const float4* iv = (const float4*)in;
    float4 a = iv[2 * i], b = iv[2 * i + 1];
    uint4 o;
    o.x = (unsigned)f2bf(a.x) | ((unsigned)f2bf(a.y) << 16);
    o.y = (unsigned)f2bf(a.z) | ((unsigned)f2bf(a.w) << 16);
    o.z = (unsigned)f2bf(b.x) | ((unsigned)f2bf(b.y) << 16);
    o.w = (unsigned)f2bf(b.z) | ((unsigned)f2bf(b.w) << 16);
    ((uint4*)out)[i] = o;
}

// Fused prep + degree count: x->bf16, four W->bf16, then appended blocks do
// the per-edge degree atomics for BOTH layers (deg zeroed by memset before).
__global__ void k_prep_cnt(const float* __restrict__ x, unsigned short* __restrict__ x_bf,
                           const float* __restrict__ W1l, const float* __restrict__ W1r,
                           const float* __restrict__ W2l, const float* __restrict__ W2r,
                           unsigned short* __restrict__ w1, unsigned short* __restrict__ w2,
                           const int* __restrict__ d1, const int* __restrict__ d2,
                           int* __restrict__ deg1, int* __restrict__ deg2,
                           int n8, int E1, int E2, int EB) {
    int i = blockIdx.x * blockDim.x + threadIdx.x;
    if (i < n8) { cvt8(x, x_bf, i); return; }
    i -= n8;
    if (i < 32768)  { cvt8(W1l, w1, i); return; }
    if (i < 65536)  { cvt8(W1r, w1 + 262144, i - 32768); return; }
    if (i < 81920)  { cvt8(W2l, w2, i - 65536); return; }
    if (i < 98304)  { cvt8(W2r, w2 + 131072, i - 81920); return; }
    i -= 98304;
    if (i < EB * 256) { if (i < E1) atomicAdd(&deg1[d1[i]], 1); return; }
    i -= EB * 256;
    if (i < E2) atomicAdd(&deg2[d2[i]], 1);
}

#define SCAN_B 256
__global__ void k_scan_partial2(const int* __restrict__ deg1, const int* __restrict__ deg2,
                                int* __restrict__ part1, int* __restrict__ part2, int n) {
    __shared__ int s[SCAN_B];
    const int* deg = blockIdx.y ? deg2 : deg1;
    int* part      = blockIdx.y ? part2 : part1;
    int i = blockIdx.x * SCAN_B + threadIdx.x;
    s[threadIdx.x] = (i < n) ? deg[i] : 0;
    __syncthreads();
    for (int off = SCAN_B / 2; off > 0; off >>= 1) {
        if (threadIdx.x < off) s[threadIdx.x] += s[threadIdx.x + off];
        __syncthreads();
    }
    if (threadIdx.x == 0) part[blockIdx.x] = s[0];
}

__global__ void k_scan_part2b(int* __restrict__ part1, int* __restrict__ part2, int nb,
                              int* __restrict__ rowptr1, int* __restrict__ rowptr2, int n) {
    __shared__ int s[SCAN_B];
    int* part   = blockIdx.x ? part2 : part1;
    int* rowptr = blockIdx.x ? rowptr2 : rowptr1;
    int v = (threadIdx.x < nb) ? part[threadIdx.x] : 0;
    s[threadIdx.x] = v;
    __syncthreads();
    for (int off = 1; off < SCAN_B; off <<= 1) {
        int t = (threadIdx.x >= off) ? s[threadIdx.x - off] : 0;
        __syncthreads();
        s[threadIdx.x] += t;
        __syncthreads();
    }
    if (threadIdx.x < nb) part[threadIdx.x] = s[threadIdx.x] - v;  // exclusive
    if (threadIdx.x == SCAN_B - 1) rowptr[n] = s[SCAN_B - 1];
}

__global__ void k_scan_final2(const int* __restrict__ deg1, const int* __restrict__ deg2,
                              const int* __restrict__ part1, const int* __restrict__ part2,
                              int* __restrict__ rowptr1, int* __restrict__ rowptr2,
                              int* __restrict__ cursor1, int* __restrict__ cursor2, int n) {
    __shared__ int s[SCAN_B];
    const int* deg  = blockIdx.y ? deg2 : deg1;
    const int* part = blockIdx.y ? part2 : part1;
    int* rowptr     = blockIdx.y ? rowptr2 : rowptr1;
    int* cursor     = blockIdx.y ? cursor2 : cursor1;
    int i = blockIdx.x * SCAN_B + threadIdx.x;
    int v = (i < n) ? deg[i] : 0;
    s[threadIdx.x] = v;
    __syncthreads();
    for (int off = 1; off < SCAN_B; off <<= 1) {
        int t = (threadIdx.x >= off) ? s[threadIdx.x - off] : 0;
        __syncthreads();
        s[threadIdx.x] += t;
        __syncthreads();
    }
    if (i < n) {
        int ex = part[blockIdx.x] + s[threadIdx.x] - v;
        rowptr[i] = ex;
        cursor[i] = ex;
    }
}

// ---------------------------------------------------------------------------
// GEMM tile body, TK=64 (verified round-9: MfmaUtil 18.3->23.0, dur -17%).
// LDS 32KB/block, 4 blocks/CU at launch_bounds(256,4). Swizzle: phys chunk =
// logical ^ (row&7); staging inverse-swizzles the global source; LDS dest
// lane-linear (global_load_lds requirement). 0 bank conflicts (measured).
#define TM 128
#define TN 128
#define TK 64

template <int NCT, int SPLIT>
__device__ __forceinline__ void gemm_tile(
        const unsigned short* __restrict__ A, const unsigned short* __restrict__ W,
        unsigned char* __restrict__ C8, unsigned short* __restrict__ C16,
        int M, int K, int NC, int id,
        unsigned short* __restrict__ As, unsigned short* __restrict__ Bs) {
    const int xcd = id & 7;
    const int s = id >> 3;
    const int row0 = ((s / NCT) * 8 + xcd) * TM;
    const int col0 = (s % NCT) * TN;
    if (row0 >= M) return;

    const int t = threadIdx.x;
    const int lane = t & 63;
    const int w = t >> 6;
    const int wr = (w >> 1) * 64;
    const int wc = (w & 1) * 64;
    const int lm = lane & 15;
    const int q = lane >> 4;             // logical k-chunk 0..3 (8 bf16 each)

    f32x4 acc[4][4];
#pragma unroll
    for (int i = 0; i < 4; ++i)
#pragma unroll
        for (int j = 0; j < 4; ++j) acc[i][j] = (f32x4){0.f, 0.f, 0.f, 0.f};

    // staging geometry
    const int sr = t >> 3;                    // 0..31 (row within 32-row segment)
    const int sc = t & 7;                     // chunk slot 0..7
    const int gx = (sc ^ (sr & 7)) * 8;       // inverse-swizzled source chunk

    #define GL(SRC, DST) __builtin_amdgcn_global_load_lds( \
        (const __attribute__((address_space(1))) unsigned int*)(SRC), \
        (__attribute__((address_space(3))) unsigned int*)(DST), 16, 0, 0)

    for (int k0 = 0; k0 < K; k0 += TK) {
#pragma unroll
        for (int L = 0; L < 4; ++L) {
            int ra = row0 + L * 32 + sr; if (ra >= M) ra = M - 1;
            GL(A + (size_t)ra * K + k0 + gx, &As[L * 2048 + t * 8]);
        }
#pragma unroll
        for (int L = 0; L < 4; ++L) {
            int rb = col0 + L * 32 + sr;      // W rows always in range
            GL(W + (size_t)rb * K + k0 + gx, &Bs[L * 2048 + t * 8]);
        }
        __syncthreads();

        short8 a[4], b[4];
        // k-step 0: logical chunks q
#pragma unroll
        for (int i = 0; i < 4; ++i) {
            int R = wr + i * 16 + lm;
            a[i] = *(const short8*)&As[R * TK + ((q ^ (R & 7)) * 8)];
        }
#pragma unroll
        for (int j = 0; j < 4; ++j) {
            int R = wc + j * 16 + lm;
            b[j] = *(const short8*)&Bs[R * TK + ((q ^ (R & 7)) * 8)];
        }
#pragma unroll
        for (int i = 0; i < 4; ++i)
#pragma unroll
            for (int j = 0; j < 4; ++j)
                acc[i][j] = __builtin_amdgcn_mfma_f32_16x16x32_bf16(a[i], b[j], acc[i][j], 0, 0, 0);
        // k-step 1: logical chunks 4+q (reuse registers)
#pragma unroll
        for (int i = 0; i < 4; ++i) {
            int R = wr + i * 16 + lm;
            a[i] = *(const short8*)&As[R * TK + (((4 + q) ^ (R & 7)) * 8)];
        }
#pragma unroll
        for (int j = 0; j < 4; ++j) {
            int R = wc + j * 16 + lm;
            b[j] = *(const short8*)&Bs[R * TK + (((4 + q) ^ (R & 7)) * 8)];
        }
#pragma unroll
        for (int i = 0; i < 4; ++i)
#pragma unroll
            for (int j = 0; j < 4; ++j)
                acc[i][j] = __builtin_amdgcn_mfma_f32_16x16x32_bf16(a[i], b[j], acc[i][j], 0, 0, 0);
        __syncthreads();
    }
    #undef GL

    // epilogue: D row = quad*4 + reg, col = lane&15. col0 is 128-aligned so
    // the fp8/bf16 split (at NC/2) is block-uniform.
    const int qr = (lane >> 4) * 4;
    const bool lo_half = SPLIT && (col0 < NC / 2);
    const int cadj = SPLIT ? NC / 2 : 0;
#pragma unroll
    for (int i = 0; i < 4; ++i) {
#pragma unroll
        for (int r = 0; r < 4; ++r) {
            int gr = row0 + wr + i * 16 + qr + r;
            if (gr >= M) continue;
#pragma unroll
            for (int j = 0; j < 4; ++j) {
                int gc = col0 + wc + j * 16 + lm;
                float v = acc[i][j][r];
                if (SPLIT && lo_half) {
                    int p = __builtin_amdgcn_cvt_pk_fp8_f32(v, v, 0, 0);
                    C8[(size_t)gr * (NC / 2) + gc] = (unsigned char)p;
                } else {
                    C16[(size_t)gr * (NC - cadj) + (gc - cadj)] = f2bf(v);
                }
            }
        }
    }
}

// Merged GEMM + CSR-fill (Bresenham-interleaved), ONE edge set per dispatch.
// Launched twice with row-halves of the L1 gemm (layer-1 edges with half 1,
// layer-2 edges with half 2): halves the rocprof top-5 visibility threshold
// (~93us -> ~48us) so second-tier kernels surface with counters.
template <int NCT, int SPLIT>
__global__ __launch_bounds__(256, 4)
void k_gemm_fill(const unsigned short* __restrict__ A, const unsigned short* __restrict__ W,
                 unsigned char* __restrict__ C8, unsigned short* __restrict__ C16,
                 int M, int K, int NC, int G, int F,
                 const int* __restrict__ src, const int* __restrict__ dst,
                 int* __restrict__ cur, int* __restrict__ col, int E) {
    __shared__ __align__(16) unsigned short As[TM * TK];
    __shared__ __align__(16) unsigned short Bs[TN * TK];

    const int bid = blockIdx.x;
    const long long T = (long long)G + F;
    const int pf = (int)(((long long)bid * F) / T);
    const bool isFill = (int)(((long long)(bid + 1) * F) / T) > pf;
    if (isFill) {
        int e = pf * 256 + threadIdx.x;
        if (e < E) {
            int p = atomicAdd(&cur[dst[e]], 1);
            __builtin_nontemporal_store(src[e], &col[p]);
        }
        return;
    }
    gemm_tile<NCT, SPLIT>(A, W, C8, C16, M, K, NC, bid - pf, As, Bs);
}

// Standalone gemm (layer 2) — identical body.
template <int NCT, int SPLIT>
__global__ __launch_bounds__(256, 4)
void k_gemm_mfma(const unsigned short* __restrict__ A, const unsigned short* __restrict__ W,
                 unsigned char* __restrict__ C8, unsigned short* __restrict__ C16,
                 int M, int K, int NC) {
    __shared__ __align__(16) unsigned short As[TM * TK];
    __shared__ __align__(16) unsigned short Bs[TN * TK];
    gemm_tile<NCT, SPLIT>(A, W, C8, C16, M, K, NC, blockIdx.x, As, Bs);
}

// ---------------------------------------------------------------------------
// Layer-1 fused epilogue: h[i] = relu( mean_j C8[j] + C16r[i] + b1 ), bf16 out.
__global__ void k_agg_relu(const unsigned char* __restrict__ C8,
                           const unsigned short* __restrict__ C16r,
                           const int* __restrict__ rowptr, const int* __restrict__ col,
                           const float* __restrict__ b1, unsigned short* __restrict__ H, int n) {
    int node = blockIdx.x * (blockDim.x >> 6) + (threadIdx.x >> 6);
    int lane = threadIdx.x & 63;
    if (node >= n) return;
    int beg = rowptr[node], end = rowptr[node + 1];
    float acc[8] = {};
    const uint2* Cv = (const uint2*)C8;   // row stride 64 uint2
    int e = beg;
    for (; e + 4 <= end; e += 4) {
        int c0 = col[e], c1 = col[e + 1], c2 = col[e + 2], c3 = col[e + 3];
        uint2 v0 = Cv[(size_t)c0 * 64 + lane];
        uint2 v1 = Cv[(size_t)c1 * 64 + lane];
        uint2 v2 = Cv[(size_t)c2 * 64 + lane];
        uint2 v3 = Cv[(size_t)c3 * 64 + lane];
        unsigned int ws[8] = {v0.x, v0.y, v1.x, v1.y, v2.x, v2.y, v3.x, v3.y};
#pragma unroll
        for (int qq = 0; qq < 8; ++qq) {
            floatx2 flo = __builtin_amdgcn_cvt_pk_f32_fp8(ws[qq], 0);
            floatx2 fhi = __builtin_amdgcn_cvt_pk_f32_fp8(ws[qq], 1);
            int base = (qq & 1) * 4;
            acc[base + 0] += flo.x; acc[base + 1] += flo.y;
            acc[base + 2] += fhi.x; acc[base + 3] += fhi.y;
        }
    }
    for (; e < end; ++e) {
        uint2 v = Cv[(size_t)col[e] * 64 + lane];
        floatx2 f0 = __builtin_amdgcn_cvt_pk_f32_fp8(v.x, 0);
        floatx2 f1 = __builtin_amdgcn_cvt_pk_f32_fp8(v.x, 1);
        floatx2 f2 = __builtin_amdgcn_cvt_pk_f32_fp8(v.y, 0);
        floatx2 f3 = __builtin_amdgcn_cvt_pk_f32_fp8(v.y, 1);
        acc[0] += f0.x; acc[1] += f0.y; acc[2] += f1.x; acc[3] += f1.y;
        acc[4] += f2.x; acc[5] += f2.y; acc[6] += f3.x; acc[7] += f3.y;
    }
    float inv = 1.0f / fmaxf((float)(end - beg), 1.0f);
    uint4 yr = ((const uint4*)C16r)[(size_t)node * 64 + lane];
    unsigned int wr[4] = {yr.x, yr.y, yr.z, yr.w};
    float4 bv0 = ((const float4*)b1)[2 * lane];
    float4 bv1 = ((const float4*)b1)[2 * lane + 1];
    float bb[8] = {bv0.x, bv0.y, bv0.z, bv0.w, bv1.x, bv1.y, bv1.z, bv1.w};
    unsigned int r[4];
#pragma unroll
    for (int qq = 0; qq < 4; ++qq) {
        float v0 = fmaxf(acc[2 * qq] * inv     + bflo(wr[qq]) + bb[2 * qq],     0.f);
        float v1 = fmaxf(acc[2 * qq + 1] * inv + bfhi(wr[qq]) + bb[2 * qq + 1], 0.f);
        r[qq] = (unsigned)f2bf(v0) | ((unsigned)f2bf(v1) << 16);
    }
    uint4 o; o.x = r[0]; o.y = r[1]; o.z = r[2]; o.w = r[3];
    ((uint4*)H)[(size_t)node * 64 + lane] = o;
}

// ---------------------------------------------------------------------------
// Layer-2 fused epilogue: out[i] = log_softmax( mean_j C8[j] + C16r[i] + b2 ).
__global__ void k_agg_lsm(const unsigned char* __restrict__ C8,
                          const unsigned short* __restrict__ C16r,
                          const int* __restrict__ rowptr, const int* __restrict__ col,
                          const float* __restrict__ b2, float* __restrict__ O, int n) {
    int node = blockIdx.x * (blockDim.x >> 6) + (threadIdx.x >> 6);
    int lane = threadIdx.x & 63;
    if (node >= n) return;
    int beg = rowptr[node], end = rowptr[node + 1];
    float acc[4] = {};
    const unsigned int* Cv = (const unsigned int*)C8;   // row stride 64 uint
    int e = beg;
    for (; e + 4 <= end; e += 4) {
        int c0 = col[e], c1 = col[e + 1], c2 = col[e + 2], c3 = col[e + 3];
        unsigned int u0 = Cv[(size_t)c0 * 64 + lane];
        unsigned int u1 = Cv[(size_t)c1 * 64 + lane];
        unsigned int u2 = Cv[(size_t)c2 * 64 + lane];
        unsigned int u3 = Cv[(size_t)c3 * 64 + lane];
        unsigned int us[4] = {u0, u1, u2, u3};
#pragma unroll
        for (int qq = 0; qq < 4; ++qq) {
            floatx2 flo = __builtin_amdgcn_cvt_pk_f32_fp8(us[qq], 0);
            floatx2 fhi = __builtin_amdgcn_cvt_pk_f32_fp8(us[qq], 1);
            acc[0] += flo.x; acc[1] += flo.y; acc[2] += fhi.x; acc[3] += fhi.y;
        }
    }
    for (; e < end; ++e) {
        unsigned int u = Cv[(size_t)col[e] * 64 + lane];
        floatx2 flo = __builtin_amdgcn_cvt_pk_f32_fp8(u, 0);
        floatx2 fhi = __builtin_amdgcn_cvt_pk_f32_fp8(u, 1);
        acc[0] += flo.x; acc[1] += flo.y; acc[2] += fhi.x; acc[3] += fhi.y;
    }
    float inv = 1.0f / fmaxf((float)(end - beg), 1.0f);
    uint2 yr = ((const uint2*)C16r)[(size_t)node * 64 + lane];
    float4 bv = ((const float4*)b2)[lane];
    float val[4];
    val[0] = acc[0] * inv + bflo(yr.x) + bv.x;
    val[1] = acc[1] * inv + bfhi(yr.x) + bv.y;
    val[2] = acc[2] * inv + bflo(yr.y) + bv.z;
    val[3] = acc[3] * inv + bfhi(yr.y) + bv.w;
    float mx = fmaxf(fmaxf(val[0], val[1]), fmaxf(val[2], val[3]));
#pragma unroll
    for (int off = 32; off > 0; off >>= 1) mx = fmaxf(mx, __shfl_xor(mx, off));
    float s = expf(val[0] - mx) + expf(val[1] - mx) + expf(val[2] - mx) + expf(val[3] - mx);
#pragma unroll
    for (int off = 32; off > 0; off >>= 1) s += __shfl_xor(s, off);
    float lse = mx + logf(s);
    float4 o = make_float4(val[0] - lse, val[1] - lse, val[2] - lse, val[3] - lse);
    ((float4*)O)[(size_t)node * 64 + lane] = o;
}

// ---------------------------------------------------------------------------
extern "C" void kernel_launch(void* const* d_in, const int* in_sizes, int n_in,
                              void* d_out, int out_size, void* d_ws, size_t ws_size,
                              hipStream_t stream) {
    const float* x   = (const float*)d_in[0];
    const int*   ei1 = (const int*)d_in[1];
    const int*   ei2 = (const int*)d_in[2];
    const float* W1l = (const float*)d_in[3];
    const float* b1  = (const float*)d_in[4];
    const float* W1r = (const float*)d_in[5];
    const float* W2l = (const float*)d_in[6];
    const float* b2  = (const float*)d_in[7];
    const float* W2r = (const float*)d_in[8];
    float* out = (float*)d_out;

    const int N  = in_sizes[0] / DIN;
    const int E1 = in_sizes[1] / 2;
    const int E2 = in_sizes[2] / 2;
    const int Emax = (E1 > E2) ? E1 : E2;
    const int NB = (N + SCAN_B - 1) / SCAN_B;
    const int EB = (Emax + 255) / 256;

    // Workspace layout
    unsigned short* x_bf  = (unsigned short*)d_ws;             // N*512 bf16
    unsigned short* h_bf  = x_bf + (size_t)N * 512;            // N*512 bf16
    unsigned char*  c1l   = (unsigned char*)(h_bf + (size_t)N * 512);  // N*512 fp8
    unsigned short* c1r   = (unsigned short*)(c1l + (size_t)N * 512);  // N*512 bf16
    unsigned char*  c2l   = c1l;                               // N*256 fp8 (aliases c1)
    unsigned short* c2r   = (unsigned short*)(c2l + (size_t)N * 256);  // N*256 bf16
    unsigned short* w1_bf = c1r + (size_t)N * 512;             // 1024*512
    unsigned short* w2_bf = w1_bf + 1024 * 512;                // 512*512
    int* rowptr1 = (int*)(w2_bf + 512 * 512);                  // N+1
    int* rowptr2 = rowptr1 + (N + 1);                          // N+1
    int* cursor1 = rowptr2 + (N + 1);                          // N
    int* cursor2 = cursor1 + N;                                // N
    int* deg1    = cursor2 + N;                                // N
    int* deg2    = deg1 + N;                                   // N
    int* part1   = deg2 + N;                                   // 256
    int* part2   = part1 + 256;                                // 256
    int* col1    = part2 + 256;                                // E1
    int* col2    = col1 + E1;                                  // E2
    (void)ws_size; (void)n_in; (void)out_size;

    // deg zeroing, then fused conversions + degree count (count2 overlaps prep)
    hipMemsetAsync(deg1, 0, (size_t)2 * N * sizeof(int), stream);
    {
        int n8 = N * 512 / 8;
        int gb = (n8 + 98304 + 255) / 256 + 2 * EB;
        k_prep_cnt<<<gb, 256, 0, stream>>>(x, x_bf, W1l, W1r, W2l, W2r, w1_bf, w2_bf,
                                           ei1 + E1, ei2 + E2, deg1, deg2, n8, E1, E2, EB);
    }

    // scans (both layers batched)
    k_scan_partial2<<<dim3(NB, 2), SCAN_B, 0, stream>>>(deg1, deg2, part1, part2, N);
    k_scan_part2b<<<2, SCAN_B, 0, stream>>>(part1, part2, NB, rowptr1, rowptr2, N);
    k_scan_final2<<<dim3(NB, 2), SCAN_B, 0, stream>>>(deg1, deg2, part1, part2,
                                                      rowptr1, rowptr2, cursor1, cursor2, N);

    // Layer 1 GEMM split into two row-halves (visibility threshold ~48us),
    // each merged with one layer's CSR fill (Bresenham-interleaved).
    {
        const int MBt = (N + TM - 1) / TM;       // total row tiles (391)
        const int MB1t = (MBt + 1) / 2;          // 196
        const int M1 = MB1t * TM < N ? MB1t * TM : N;   // 25088
        const int M2 = N - M1;                   // 24912
        const int G1 = ((MB1t + 7) / 8) * 8 * 8; // 1600 (NCT=8)
        const int F1 = (E1 + 255) / 256;
        k_gemm_fill<8, 1><<<G1 + F1, 256, 0, stream>>>(
            x_bf, w1_bf, c1l, c1r, M1, DIN, 1024, G1, F1,
            ei1, ei1 + E1, cursor1, col1, E1);
        if (M2 > 0) {
            const int MB2t = (M2 + TM - 1) / TM;
            const int G2 = ((MB2t + 7) / 8) * 8 * 8;
            const int F2 = (E2 + 255) / 256;
            k_gemm_fill<8, 1><<<G2 + F2, 256, 0, stream>>>(
                x_bf + (size_t)M1 * DIN, w1_bf,
                c1l + (size_t)M1 * 512, c1r + (size_t)M1 * 512,
                M2, DIN, 1024, G2, F2,
                ei2, ei2 + E2, cursor2, col2, E2);
        } else {
            // degenerate small-N case: fill layer-2 standalone via fill-only grid
            const int F2 = (E2 + 255) / 256;
            k_gemm_fill<8, 1><<<F2, 256, 0, stream>>>(
                x_bf, w1_bf, c1l, c1r, 0, DIN, 1024, 0, F2,
                ei2, ei2 + E2, cursor2, col2, E2);
        }
    }
    k_agg_relu<<<(N + 3) / 4, 256, 0, stream>>>(c1l, c1r, rowptr1, col1, b1, h_bf, N);

    // Layer 2: [y_l|y_r] = h @ [W2l;W2r]^T; y_l -> fp8, y_r -> bf16.
    {
        const int MBt = (N + TM - 1) / TM;
        const int G8 = (MBt + 7) / 8;
        k_gemm_mfma<4, 1><<<G8 * 8 * 4, 256, 0, stream>>>(h_bf, w2_bf, c2l, c2r, N, DHID, 512);
    }
    k_agg_lsm<<<(N + 3) / 4, 256, 0, stream>>>(c2l, c2r, rowptr2, col2, b2, out, N);
}

// Round 11
// 413.056 us; speedup vs baseline: 1.1232x; 1.1232x over previous
//
#include <hip/hip_runtime.h>
#include <math.h>

#define DIN  512
#define DHID 512
#define DOUT 256

typedef __attribute__((ext_vector_type(8))) short short8;
typedef __attribute__((ext_vector_type(4))) float f32x4;
typedef __attribute__((ext_vector_type(2))) float floatx2;

__device__ __forceinline__ unsigned short f2bf(float f) {
    unsigned int u = __float_as_uint(f);
    u += 0x7fffu + ((u >> 16) & 1u);
    return (unsigned short)(u >> 16);
}
__device__ __forceinline__ float bflo(unsigned int w) { return __uint_as_float(w << 16); }
__device__ __forceinline__ float bfhi(unsigned int w) { return __uint_as_float(w & 0xffff0000u); }

// ---------------------------------------------------------------------------
// fp32 -> bf16, 8 elems per index i
__device__ __forceinline__ void cvt8(const float* __restrict__ in,
                                     unsigned short* __restrict__ out, int i) {
    const float4* iv = (const float4*)in;
    float4 a = iv[2 * i], b = iv[2 * i + 1];
    uint4 o;
    o.x = (unsigned)f2bf(a.x) | ((unsigned)f2bf(a.y) << 16);
    o.y = (unsigned)f2bf(a.z) | ((unsigned)f2bf(a.w) << 16);
    o.z = (unsigned)f2bf(b.x) | ((unsigned)f2bf(b.y) << 16);
    o.w = (unsigned)f2bf(b.z) | ((unsigned)f2bf(b.w) << 16);
    ((uint4*)out)[i] = o;
}

// Fused prep + degree count, Bresenham-INTERLEAVED (round-10 counters showed
// the appended edge-count blocks serialized after the conversion blocks:
// VALUBusy 3.4%, HBM 21% -> phase serialization, 82.8us). Interleaving puts
// latency-bound atomic blocks on CUs concurrently with streaming conversion
// blocks: atomic latency hides under conversion bandwidth.
__global__ void k_prep_cnt(const float* __restrict__ x, unsigned short* __restrict__ x_bf,
                           const float* __restrict__ W1l, const float* __restrict__ W1r,
                           const float* __restrict__ W2l, const float* __restrict__ W2r,
                           unsigned short* __restrict__ w1, unsigned short* __restrict__ w2,
                           const int* __restrict__ d1, const int* __restrict__ d2,
                           int* __restrict__ deg1, int* __restrict__ deg2,
                           int n8, int E1, int E2, int EB, int CB, int FB) {
    const int bid = blockIdx.x;
    const long long T = (long long)CB + FB;
    const int pf = (int)(((long long)bid * FB) / T);
    const bool isFill = (int)(((long long)(bid + 1) * FB) / T) > pf;
    if (isFill) {
        const int f = pf;
        if (f < EB) {
            int e = f * 256 + threadIdx.x;
            if (e < E1) atomicAdd(&deg1[d1[e]], 1);
        } else {
            int e = (f - EB) * 256 + threadIdx.x;
            if (e < E2) atomicAdd(&deg2[d2[e]], 1);
        }
        return;
    }
    int i = (bid - pf) * 256 + threadIdx.x;
    if (i < n8) { cvt8(x, x_bf, i); return; }
    i -= n8;
    if (i < 32768)  { cvt8(W1l, w1, i); return; }
    if (i < 65536)  { cvt8(W1r, w1 + 262144, i - 32768); return; }
    if (i < 81920)  { cvt8(W2l, w2, i - 65536); return; }
    if (i < 98304)  { cvt8(W2r, w2 + 131072, i - 81920); return; }
}

#define SCAN_B 256
__global__ void k_scan_partial2(const int* __restrict__ deg1, const int* __restrict__ deg2,
                                int* __restrict__ part1, int* __restrict__ part2, int n) {
    __shared__ int s[SCAN_B];
    const int* deg = blockIdx.y ? deg2 : deg1;
    int* part      = blockIdx.y ? part2 : part1;
    int i = blockIdx.x * SCAN_B + threadIdx.x;
    s[threadIdx.x] = (i < n) ? deg[i] : 0;
    __syncthreads();
    for (int off = SCAN_B / 2; off > 0; off >>= 1) {
        if (threadIdx.x < off) s[threadIdx.x] += s[threadIdx.x + off];
        __syncthreads();
    }
    if (threadIdx.x == 0) part[blockIdx.x] = s[0];
}

__global__ void k_scan_part2b(int* __restrict__ part1, int* __restrict__ part2, int nb,
                              int* __restrict__ rowptr1, int* __restrict__ rowptr2, int n) {
    __shared__ int s[SCAN_B];
    int* part   = blockIdx.x ? part2 : part1;
    int* rowptr = blockIdx.x ? rowptr2 : rowptr1;
    int v = (threadIdx.x < nb) ? part[threadIdx.x] : 0;
    s[threadIdx.x] = v;
    __syncthreads();
    for (int off = 1; off < SCAN_B; off <<= 1) {
        int t = (threadIdx.x >= off) ? s[threadIdx.x - off] : 0;
        __syncthreads();
        s[threadIdx.x] += t;
        __syncthreads();
    }
    if (threadIdx.x < nb) part[threadIdx.x] = s[threadIdx.x] - v;  // exclusive
    if (threadIdx.x == SCAN_B - 1) rowptr[n] = s[SCAN_B - 1];
}

__global__ void k_scan_final2(const int* __restrict__ deg1, const int* __restrict__ deg2,
                              const int* __restrict__ part1, const int* __restrict__ part2,
                              int* __restrict__ rowptr1, int* __restrict__ rowptr2,
                              int* __restrict__ cursor1, int* __restrict__ cursor2, int n) {
    __shared__ int s[SCAN_B];
    const int* deg  = blockIdx.y ? deg2 : deg1;
    const int* part = blockIdx.y ? part2 : part1;
    int* rowptr     = blockIdx.y ? rowptr2 : rowptr1;
    int* cursor     = blockIdx.y ? cursor2 : cursor1;
    int i = blockIdx.x * SCAN_B + threadIdx.x;
    int v = (i < n) ? deg[i] : 0;
    s[threadIdx.x] = v;
    __syncthreads();
    for (int off = 1; off < SCAN_B; off <<= 1) {
        int t = (threadIdx.x >= off) ? s[threadIdx.x - off] : 0;
        __syncthreads();
        s[threadIdx.x] += t;
        __syncthreads();
    }
    if (i < n) {
        int ex = part[blockIdx.x] + s[threadIdx.x] - v;
        rowptr[i] = ex;
        cursor[i] = ex;
    }
}

// ---------------------------------------------------------------------------
// GEMM tile body, TK=64 (verified round-9: MfmaUtil 18.3->23.0, dur -17%).
// LDS 32KB/block, 4 blocks/CU at launch_bounds(256,4). Swizzle: phys chunk =
// logical ^ (row&7); staging inverse-swizzles the global source; LDS dest
// lane-linear (global_load_lds requirement). 0 bank conflicts (measured).
#define TM 128
#define TN 128
#define TK 64

template <int NCT, int SPLIT>
__device__ __forceinline__ void gemm_tile(
        const unsigned short* __restrict__ A, const unsigned short* __restrict__ W,
        unsigned char* __restrict__ C8, unsigned short* __restrict__ C16,
        int M, int K, int NC, int id,
        unsigned short* __restrict__ As, unsigned short* __restrict__ Bs) {
    const int xcd = id & 7;
    const int s = id >> 3;
    const int row0 = ((s / NCT) * 8 + xcd) * TM;
    const int col0 = (s % NCT) * TN;
    if (row0 >= M) return;

    const int t = threadIdx.x;
    const int lane = t & 63;
    const int w = t >> 6;
    const int wr = (w >> 1) * 64;
    const int wc = (w & 1) * 64;
    const int lm = lane & 15;
    const int q = lane >> 4;             // logical k-chunk 0..3 (8 bf16 each)

    f32x4 acc[4][4];
#pragma unroll
    for (int i = 0; i < 4; ++i)
#pragma unroll
        for (int j = 0; j < 4; ++j) acc[i][j] = (f32x4){0.f, 0.f, 0.f, 0.f};

    // staging geometry
    const int sr = t >> 3;                    // 0..31 (row within 32-row segment)
    const int sc = t & 7;                     // chunk slot 0..7
    const int gx = (sc ^ (sr & 7)) * 8;       // inverse-swizzled source chunk

    #define GL(SRC, DST) __builtin_amdgcn_global_load_lds( \
        (const __attribute__((address_space(1))) unsigned int*)(SRC), \
        (__attribute__((address_space(3))) unsigned int*)(DST), 16, 0, 0)

    for (int k0 = 0; k0 < K; k0 += TK) {
#pragma unroll
        for (int L = 0; L < 4; ++L) {
            int ra = row0 + L * 32 + sr; if (ra >= M) ra = M - 1;
            GL(A + (size_t)ra * K + k0 + gx, &As[L * 2048 + t * 8]);
        }
#pragma unroll
        for (int L = 0; L < 4; ++L) {
            int rb = col0 + L * 32 + sr;      // W rows always in range
            GL(W + (size_t)rb * K + k0 + gx, &Bs[L * 2048 + t * 8]);
        }
        __syncthreads();

        short8 a[4], b[4];
        // k-step 0: logical chunks q
#pragma unroll
        for (int i = 0; i < 4; ++i) {
            int R = wr + i * 16 + lm;
            a[i] = *(const short8*)&As[R * TK + ((q ^ (R & 7)) * 8)];
        }
#pragma unroll
        for (int j = 0; j < 4; ++j) {
            int R = wc + j * 16 + lm;
            b[j] = *(const short8*)&Bs[R * TK + ((q ^ (R & 7)) * 8)];
        }
#pragma unroll
        for (int i = 0; i < 4; ++i)
#pragma unroll
            for (int j = 0; j < 4; ++j)
                acc[i][j] = __builtin_amdgcn_mfma_f32_16x16x32_bf16(a[i], b[j], acc[i][j], 0, 0, 0);
        // k-step 1: logical chunks 4+q (reuse registers)
#pragma unroll
        for (int i = 0; i < 4; ++i) {
            int R = wr + i * 16 + lm;
            a[i] = *(const short8*)&As[R * TK + (((4 + q) ^ (R & 7)) * 8)];
        }
#pragma unroll
        for (int j = 0; j < 4; ++j) {
            int R = wc + j * 16 + lm;
            b[j] = *(const short8*)&Bs[R * TK + (((4 + q) ^ (R & 7)) * 8)];
        }
#pragma unroll
        for (int i = 0; i < 4; ++i)
#pragma unroll
            for (int j = 0; j < 4; ++j)
                acc[i][j] = __builtin_amdgcn_mfma_f32_16x16x32_bf16(a[i], b[j], acc[i][j], 0, 0, 0);
        __syncthreads();
    }
    #undef GL

    // epilogue: D row = quad*4 + reg, col = lane&15. col0 is 128-aligned so
    // the fp8/bf16 split (at NC/2) is block-uniform.
    const int qr = (lane >> 4) * 4;
    const bool lo_half = SPLIT && (col0 < NC / 2);
    const int cadj = SPLIT ? NC / 2 : 0;
#pragma unroll
    for (int i = 0; i < 4; ++i) {
#pragma unroll
        for (int r = 0; r < 4; ++r) {
            int gr = row0 + wr + i * 16 + qr + r;
            if (gr >= M) continue;
#pragma unroll
            for (int j = 0; j < 4; ++j) {
                int gc = col0 + wc + j * 16 + lm;
                float v = acc[i][j][r];
                if (SPLIT && lo_half) {
                    int p = __builtin_amdgcn_cvt_pk_fp8_f32(v, v, 0, 0);
                    C8[(size_t)gr * (NC / 2) + gc] = (unsigned char)p;
                } else {
                    C16[(size_t)gr * (NC - cadj) + (gc - cadj)] = f2bf(v);
                }
            }
        }
    }
}

// Merged GEMM + BOTH layers' CSR-fill (Bresenham-interleaved; round-9 config,
// measured 95.9us). Fill's scattered traffic runs in gemm's idle HBM slots.
template <int NCT, int SPLIT>
__global__ __launch_bounds__(256, 4)
void k_gemm_fill(const unsigned short* __restrict__ A, const unsigned short* __restrict__ W,
                 unsigned char* __restrict__ C8, unsigned short* __restrict__ C16,
                 int M, int K, int NC, int G, int F,
                 const int* __restrict__ s1, const int* __restrict__ d1,
                 const int* __restrict__ s2, const int* __restrict__ d2,
                 int* __restrict__ cur1, int* __restrict__ cur2,
                 int* __restrict__ col1, int* __restrict__ col2,
                 int E1, int E2, int EB) {
    __shared__ __align__(16) unsigned short As[TM * TK];
    __shared__ __align__(16) unsigned short Bs[TN * TK];

    const int bid = blockIdx.x;
    const long long T = (long long)G + F;
    const int pf = (int)(((long long)bid * F) / T);
    const bool isFill = (int)(((long long)(bid + 1) * F) / T) > pf;
    if (isFill) {
        const int f = pf;
        if (f < EB) {
            int e = f * 256 + threadIdx.x;
            if (e < E1) {
                int p = atomicAdd(&cur1[d1[e]], 1);
                __builtin_nontemporal_store(s1[e], &col1[p]);
            }
        } else {
            int e = (f - EB) * 256 + threadIdx.x;
            if (e < E2) {
                int p = atomicAdd(&cur2[d2[e]], 1);
                __builtin_nontemporal_store(s2[e], &col2[p]);
            }
        }
        return;
    }
    gemm_tile<NCT, SPLIT>(A, W, C8, C16, M, K, NC, bid - pf, As, Bs);
}

// Standalone gemm (layer 2) — identical body.
template <int NCT, int SPLIT>
__global__ __launch_bounds__(256, 4)
void k_gemm_mfma(const unsigned short* __restrict__ A, const unsigned short* __restrict__ W,
                 unsigned char* __restrict__ C8, unsigned short* __restrict__ C16,
                 int M, int K, int NC) {
    __shared__ __align__(16) unsigned short As[TM * TK];
    __shared__ __align__(16) unsigned short Bs[TN * TK];
    gemm_tile<NCT, SPLIT>(A, W, C8, C16, M, K, NC, blockIdx.x, As, Bs);
}

// ---------------------------------------------------------------------------
// Layer-1 fused epilogue: h[i] = relu( mean_j C8[j] + C16r[i] + b1 ), bf16 out.
__global__ void k_agg_relu(const unsigned char* __restrict__ C8,
                           const unsigned short* __restrict__ C16r,
                           const int* __restrict__ rowptr, const int* __restrict__ col,
                           const float* __restrict__ b1, unsigned short* __restrict__ H, int n) {
    int node = blockIdx.x * (blockDim.x >> 6) + (threadIdx.x >> 6);
    int lane = threadIdx.x & 63;
    if (node >= n) return;
    int beg = rowptr[node], end = rowptr[node + 1];
    float acc[8] = {};
    const uint2* Cv = (const uint2*)C8;   // row stride 64 uint2
    int e = beg;
    for (; e + 4 <= end; e += 4) {
        int c0 = col[e], c1 = col[e + 1], c2 = col[e + 2], c3 = col[e + 3];
        uint2 v0 = Cv[(size_t)c0 * 64 + lane];
        uint2 v1 = Cv[(size_t)c1 * 64 + lane];
        uint2 v2 = Cv[(size_t)c2 * 64 + lane];
        uint2 v3 = Cv[(size_t)c3 * 64 + lane];
        unsigned int ws[8] = {v0.x, v0.y, v1.x, v1.y, v2.x, v2.y, v3.x, v3.y};
#pragma unroll
        for (int qq = 0; qq < 8; ++qq) {
            floatx2 flo = __builtin_amdgcn_cvt_pk_f32_fp8(ws[qq], 0);
            floatx2 fhi = __builtin_amdgcn_cvt_pk_f32_fp8(ws[qq], 1);
            int base = (qq & 1) * 4;
            acc[base + 0] += flo.x; acc[base + 1] += flo.y;
            acc[base + 2] += fhi.x; acc[base + 3] += fhi.y;
        }
    }
    for (; e < end; ++e) {
        uint2 v = Cv[(size_t)col[e] * 64 + lane];
        floatx2 f0 = __builtin_amdgcn_cvt_pk_f32_fp8(v.x, 0);
        floatx2 f1 = __builtin_amdgcn_cvt_pk_f32_fp8(v.x, 1);
        floatx2 f2 = __builtin_amdgcn_cvt_pk_f32_fp8(v.y, 0);
        floatx2 f3 = __builtin_amdgcn_cvt_pk_f32_fp8(v.y, 1);
        acc[0] += f0.x; acc[1] += f0.y; acc[2] += f1.x; acc[3] += f1.y;
        acc[4] += f2.x; acc[5] += f2.y; acc[6] += f3.x; acc[7] += f3.y;
    }
    float inv = 1.0f / fmaxf((float)(end - beg), 1.0f);
    uint4 yr = ((const uint4*)C16r)[(size_t)node * 64 + lane];
    unsigned int wr[4] = {yr.x, yr.y, yr.z, yr.w};
    float4 bv0 = ((const float4*)b1)[2 * lane];
    float4 bv1 = ((const float4*)b1)[2 * lane + 1];
    float bb[8] = {bv0.x, bv0.y, bv0.z, bv0.w, bv1.x, bv1.y, bv1.z, bv1.w};
    unsigned int r[4];
#pragma unroll
    for (int qq = 0; qq < 4; ++qq) {
        float v0 = fmaxf(acc[2 * qq] * inv     + bflo(wr[qq]) + bb[2 * qq],     0.f);
        float v1 = fmaxf(acc[2 * qq + 1] * inv + bfhi(wr[qq]) + bb[2 * qq + 1], 0.f);
        r[qq] = (unsigned)f2bf(v0) | ((unsigned)f2bf(v1) << 16);
    }
    uint4 o; o.x = r[0]; o.y = r[1]; o.z = r[2]; o.w = r[3];
    ((uint4*)H)[(size_t)node * 64 + lane] = o;
}

// ---------------------------------------------------------------------------
// Layer-2 fused epilogue: out[i] = log_softmax( mean_j C8[j] + C16r[i] + b2 ).
__global__ void k_agg_lsm(const unsigned char* __restrict__ C8,
                          const unsigned short* __restrict__ C16r,
                          const int* __restrict__ rowptr, const int* __restrict__ col,
                          const float* __restrict__ b2, float* __restrict__ O, int n) {
    int node = blockIdx.x * (blockDim.x >> 6) + (threadIdx.x >> 6);
    int lane = threadIdx.x & 63;
    if (node >= n) return;
    int beg = rowptr[node], end = rowptr[node + 1];
    float acc[4] = {};
    const unsigned int* Cv = (const unsigned int*)C8;   // row stride 64 uint
    int e = beg;
    for (; e + 4 <= end; e += 4) {
        int c0 = col[e], c1 = col[e + 1], c2 = col[e + 2], c3 = col[e + 3];
        unsigned int u0 = Cv[(size_t)c0 * 64 + lane];
        unsigned int u1 = Cv[(size_t)c1 * 64 + lane];
        unsigned int u2 = Cv[(size_t)c2 * 64 + lane];
        unsigned int u3 = Cv[(size_t)c3 * 64 + lane];
        unsigned int us[4] = {u0, u1, u2, u3};
#pragma unroll
        for (int qq = 0; qq < 4; ++qq) {
            floatx2 flo = __builtin_amdgcn_cvt_pk_f32_fp8(us[qq], 0);
            floatx2 fhi = __builtin_amdgcn_cvt_pk_f32_fp8(us[qq], 1);
            acc[0] += flo.x; acc[1] += flo.y; acc[2] += fhi.x; acc[3] += fhi.y;
        }
    }
    for (; e < end; ++e) {
        unsigned int u = Cv[(size_t)col[e] * 64 + lane];
        floatx2 flo = __builtin_amdgcn_cvt_pk_f32_fp8(u, 0);
        floatx2 fhi = __builtin_amdgcn_cvt_pk_f32_fp8(u, 1);
        acc[0] += flo.x; acc[1] += flo.y; acc[2] += fhi.x; acc[3] += fhi.y;
    }
    float inv = 1.0f / fmaxf((float)(end - beg), 1.0f);
    uint2 yr = ((const uint2*)C16r)[(size_t)node * 64 + lane];
    float4 bv = ((const float4*)b2)[lane];
    float val[4];
    val[0] = acc[0] * inv + bflo(yr.x) + bv.x;
    val[1] = acc[1] * inv + bfhi(yr.x) + bv.y;
    val[2] = acc[2] * inv + bflo(yr.y) + bv.z;
    val[3] = acc[3] * inv + bfhi(yr.y) + bv.w;
    float mx = fmaxf(fmaxf(val[0], val[1]), fmaxf(val[2], val[3]));
#pragma unroll
    for (int off = 32; off > 0; off >>= 1) mx = fmaxf(mx, __shfl_xor(mx, off));
    float s = expf(val[0] - mx) + expf(val[1] - mx) + expf(val[2] - mx) + expf(val[3] - mx);
#pragma unroll
    for (int off = 32; off > 0; off >>= 1) s += __shfl_xor(s, off);
    float lse = mx + logf(s);
    float4 o = make_float4(val[0] - lse, val[1] - lse, val[2] - lse, val[3] - lse);
    ((float4*)O)[(size_t)node * 64 + lane] = o;
}

// ---------------------------------------------------------------------------
extern "C" void kernel_launch(void* const* d_in, const int* in_sizes, int n_in,
                              void* d_out, int out_size, void* d_ws, size_t ws_size,
                              hipStream_t stream) {
    const float* x   = (const float*)d_in[0];
    const int*   ei1 = (const int*)d_in[1];
    const int*   ei2 = (const int*)d_in[2];
    const float* W1l = (const float*)d_in[3];
    const float* b1  = (const float*)d_in[4];
    const float* W1r = (const float*)d_in[5];
    const float* W2l = (const float*)d_in[6];
    const float* b2  = (const float*)d_in[7];
    const float* W2r = (const float*)d_in[8];
    float* out = (float*)d_out;

    const int N  = in_sizes[0] / DIN;
    const int E1 = in_sizes[1] / 2;
    const int E2 = in_sizes[2] / 2;
    const int Emax = (E1 > E2) ? E1 : E2;
    const int NB = (N + SCAN_B - 1) / SCAN_B;
    const int EB = (Emax + 255) / 256;

    // Workspace layout
    unsigned short* x_bf  = (unsigned short*)d_ws;             // N*512 bf16
    unsigned short* h_bf  = x_bf + (size_t)N * 512;            // N*512 bf16
    unsigned char*  c1l   = (unsigned char*)(h_bf + (size_t)N * 512);  // N*512 fp8
    unsigned short* c1r   = (unsigned short*)(c1l + (size_t)N * 512);  // N*512 bf16
    unsigned char*  c2l   = c1l;                               // N*256 fp8 (aliases c1)
    unsigned short* c2r   = (unsigned short*)(c2l + (size_t)N * 256);  // N*256 bf16
    unsigned short* w1_bf = c1r + (size_t)N * 512;             // 1024*512
    unsigned short* w2_bf = w1_bf + 1024 * 512;                // 512*512
    int* rowptr1 = (int*)(w2_bf + 512 * 512);                  // N+1
    int* rowptr2 = rowptr1 + (N + 1);                          // N+1
    int* cursor1 = rowptr2 + (N + 1);                          // N
    int* cursor2 = cursor1 + N;                                // N
    int* deg1    = cursor2 + N;                                // N
    int* deg2    = deg1 + N;                                   // N
    int* part1   = deg2 + N;                                   // 256
    int* part2   = part1 + 256;                                // 256
    int* col1    = part2 + 256;                                // E1
    int* col2    = col1 + E1;                                  // E2
    (void)ws_size; (void)n_in; (void)out_size;

    // deg zeroing, then fused conversions + degree count (Bresenham-interleaved)
    hipMemsetAsync(deg1, 0, (size_t)2 * N * sizeof(int), stream);
    {
        int n8 = N * 512 / 8;
        int CB = (n8 + 98304 + 255) / 256;
        int FB = 2 * EB;
        k_prep_cnt<<<CB + FB, 256, 0, stream>>>(x, x_bf, W1l, W1r, W2l, W2r, w1_bf, w2_bf,
                                                ei1 + E1, ei2 + E2, deg1, deg2,
                                                n8, E1, E2, EB, CB, FB);
    }

    // scans (both layers batched)
    k_scan_partial2<<<dim3(NB, 2), SCAN_B, 0, stream>>>(deg1, deg2, part1, part2, N);
    k_scan_part2b<<<2, SCAN_B, 0, stream>>>(part1, part2, NB, rowptr1, rowptr2, N);
    k_scan_final2<<<dim3(NB, 2), SCAN_B, 0, stream>>>(deg1, deg2, part1, part2,
                                                      rowptr1, rowptr2, cursor1, cursor2, N);

    const int MB = (N + TM - 1) / TM;            // 391 row tiles
    const int G8 = (MB + 7) / 8;                 // 49 groups of 8

    // Layer 1 GEMM merged with BOTH layers' CSR fill (Bresenham-interleaved).
    {
        const int G = G8 * 8 * 8;                // 3136 gemm blocks (NCT=8)
        const int F = 2 * EB;                    // fill blocks, both layers
        k_gemm_fill<8, 1><<<G + F, 256, 0, stream>>>(
            x_bf, w1_bf, c1l, c1r, N, DIN, 1024, G, F,
            ei1, ei1 + E1, ei2, ei2 + E2, cursor1, cursor2, col1, col2, E1, E2, EB);
    }
    k_agg_relu<<<(N + 3) / 4, 256, 0, stream>>>(c1l, c1r, rowptr1, col1, b1, h_bf, N);

    // Layer 2: [y_l|y_r] = h @ [W2l;W2r]^T; y_l -> fp8, y_r -> bf16.
    k_gemm_mfma<4, 1><<<G8 * 8 * 4, 256, 0, stream>>>(h_bf, w2_bf, c2l, c2r, N, DHID, 512);
    k_agg_lsm<<<(N + 3) / 4, 256, 0, stream>>>(c2l, c2r, rowptr2, col2, b2, out, N);
}